// Round 7
// baseline (662.049 us; speedup 1.0000x reference)
//
#include <hip/hip_runtime.h>
#include <stdint.h>

#define HD 8
#define DD 64
#define BSHIFT 8            // bucket covers 256 consecutive target nodes
#define BRANGE 256
#define NBMAX 512

// Native clang vector types.
typedef float  vf4 __attribute__((ext_vector_type(4)));

// Monotone float->uint mapping so unsigned atomicMax implements float max.
__device__ __forceinline__ unsigned fmap(float f) {
    unsigned u = __float_as_uint(f);
    return u ^ (unsigned)(((int)u >> 31) | 0x80000000);
}
__device__ __forceinline__ float funmap(unsigned u) {
    u ^= ((int)u < 0) ? 0x80000000u : 0xFFFFFFFFu;
    return __uint_as_float(u);
}
#define FMAP_NEG_INF 0x007FFFFFu   // maps back to -inf

// bf16 helpers. Slot layout per node (4 u32 words): word g = (bf16 h=g) | (bf16 h=g+4)<<16.
__device__ __forceinline__ unsigned pack_bf16_rne(float a, float b) {
    unsigned ua = __float_as_uint(a); ua += 0x7FFF + ((ua >> 16) & 1);
    unsigned ub = __float_as_uint(b); ub += 0x7FFF + ((ub >> 16) & 1);
    return (ua >> 16) | (ub & 0xFFFF0000u);
}
__device__ __forceinline__ float bf_lo(unsigned u) { return __uint_as_float(u << 16); }
__device__ __forceinline__ float bf_hi(unsigned u) { return __uint_as_float(u & 0xFFFF0000u); }

// Phase A: t_pk[n] = packed bf16 tanh(X[n,h,:] . W[:,h]); init m_u slots to mapped(-inf);
// zero the NB per-bucket record counters. (UNCHANGED from round 6 — probe comparability.)
__global__ __launch_bounds__(256) void attn_tanh_kernel(
    const float* __restrict__ X, const float* __restrict__ Wk,
    unsigned* __restrict__ t_pk, uint2* __restrict__ m_init,
    unsigned* __restrict__ gcnt, int NB, int N)
{
    __shared__ float Ws[DD * HD];   // W[d*8+h], 2 KB
    int tid = threadIdx.x;
    for (int i = tid; i < DD * HD; i += 256) Ws[i] = Wk[i];

    int gid = blockIdx.x * 256 + tid;
    if (gcnt != nullptr && gid < NB) gcnt[gid] = 0;

    __syncthreads();

    int wave = tid >> 6, lane = tid & 63;
    int n0 = (blockIdx.x * 4 + wave) * 2;
    if (n0 >= N) return;
    bool two = (n0 + 1 < N);

    const vf4* Xa = (const vf4*)X + (size_t)n0 * 128;  // 512 floats/node
    vf4 z = {0.f, 0.f, 0.f, 0.f};
    vf4 xv0 = Xa[lane];
    vf4 xv1 = Xa[64 + lane];
    vf4 xv2 = two ? Xa[128 + lane] : z;
    vf4 xv3 = two ? Xa[192 + lane] : z;

    int h0 = lane >> 4, d0 = (lane & 15) << 2;
    int h1 = 4 + h0;
    float w00 = Ws[(d0 + 0) * HD + h0], w01 = Ws[(d0 + 1) * HD + h0],
          w02 = Ws[(d0 + 2) * HD + h0], w03 = Ws[(d0 + 3) * HD + h0];
    float w10 = Ws[(d0 + 0) * HD + h1], w11 = Ws[(d0 + 1) * HD + h1],
          w12 = Ws[(d0 + 2) * HD + h1], w13 = Ws[(d0 + 3) * HD + h1];

    float p0 = xv0.x * w00 + xv0.y * w01 + xv0.z * w02 + xv0.w * w03;
    float p1 = xv1.x * w10 + xv1.y * w11 + xv1.z * w12 + xv1.w * w13;
    float p2 = xv2.x * w00 + xv2.y * w01 + xv2.z * w02 + xv2.w * w03;
    float p3 = xv3.x * w10 + xv3.y * w11 + xv3.z * w12 + xv3.w * w13;

    for (int off = 8; off; off >>= 1) {
        p0 += __shfl_xor(p0, off);
        p1 += __shfl_xor(p1, off);
        p2 += __shfl_xor(p2, off);
        p3 += __shfl_xor(p3, off);
    }
    if ((lane & 15) == 0) {
        int g = lane >> 4;
        t_pk[(size_t)n0 * 4 + g] = pack_bf16_rne(tanhf(p0), tanhf(p1));
        m_init[(size_t)n0 * 4 + g] = make_uint2(FMAP_NEG_INF, FMAP_NEG_INF);
        if (two) {
            t_pk[(size_t)(n0 + 1) * 4 + g] = pack_bf16_rne(tanhf(p2), tanhf(p3));
            m_init[(size_t)(n0 + 1) * 4 + g] = make_uint2(FMAP_NEG_INF, FMAP_NEG_INF);
        }
    }
}

// Pass 1 (UNCHANGED from round 6): bin edges by target bucket.
__global__ __launch_bounds__(256) void bin_kernel(
    const int* __restrict__ sources, const int* __restrict__ targets,
    unsigned* __restrict__ gcnt, unsigned* __restrict__ buf,
    const uint4* __restrict__ t_pk4, unsigned* __restrict__ m_u,
    int NB, int CAPB, int SRC_BITS, int E)
{
    __shared__ unsigned whist[4][NBMAX];   // 8 KB: per-wave hist, then per-wave cursor
    int tid = threadIdx.x;
    int wv  = tid >> 6;
    for (int i = tid; i < 4 * NBMAX; i += 256) ((unsigned*)whist)[i] = 0;
    __syncthreads();

    int e0 = blockIdx.x * 4096;
    #pragma unroll
    for (int k = 0; k < 16; ++k) {
        int e = e0 + k * 256 + tid;
        if (e < E) atomicAdd(&whist[wv][targets[e] >> BSHIFT], 1u);
    }
    __syncthreads();

    for (int i = tid; i < NB; i += 256) {
        unsigned h0 = whist[0][i], h1 = whist[1][i], h2 = whist[2][i], h3 = whist[3][i];
        unsigned tot = h0 + h1 + h2 + h3;
        if (tot) {
            unsigned g = atomicAdd(gcnt + i, tot);
            whist[0][i] = g;
            whist[1][i] = g + h0;
            whist[2][i] = g + h0 + h1;
            whist[3][i] = g + h0 + h1 + h2;
        }
    }
    __syncthreads();

    #pragma unroll
    for (int k = 0; k < 16; ++k) {
        int e = e0 + k * 256 + tid;
        if (e < E) {
            int tg = targets[e];            // L2/L1-hot from the count pass
            int s  = sources[e];
            int b  = tg >> BSHIFT;
            unsigned pos = atomicAdd(&whist[wv][b], 1u);   // absolute index
            if (pos < (unsigned)CAPB) {
                buf[(size_t)b * CAPB + pos] =
                    ((unsigned)(tg & (BRANGE - 1)) << SRC_BITS) | (unsigned)s;
            } else {
                uint4 tv = t_pk4[s];
                unsigned* mp = m_u + (size_t)tg * HD;
                atomicMax(mp + 0, fmap(bf_lo(tv.x)));
                atomicMax(mp + 1, fmap(bf_hi(tv.x)));
                atomicMax(mp + 2, fmap(bf_lo(tv.y)));
                atomicMax(mp + 3, fmap(bf_hi(tv.y)));
                atomicMax(mp + 4, fmap(bf_lo(tv.z)));
                atomicMax(mp + 5, fmap(bf_hi(tv.z)));
                atomicMax(mp + 6, fmap(bf_lo(tv.w)));
                atomicMax(mp + 7, fmap(bf_hi(tv.w)));
            }
        }
    }
}

// Pass 2 (UNCHANGED from round 6): per-bucket LDS max-table reduce.
#define MTS 9
__global__ __launch_bounds__(512) void reduce_kernel(
    const unsigned* __restrict__ gcnt, const unsigned* __restrict__ buf,
    const uint4* __restrict__ t_pk4, const unsigned* __restrict__ m_u,
    uint4* __restrict__ m_pk, int CAPB, int SRC_BITS, int N)
{
    __shared__ unsigned mt[BRANGE * MTS];   // 9.2 KB
    int tid = threadIdx.x;
    int b = blockIdx.x;
    for (int i = tid; i < BRANGE * MTS; i += 512) mt[i] = FMAP_NEG_INF;
    __syncthreads();

    unsigned cnt_raw = gcnt[b];
    bool overflow = cnt_raw > (unsigned)CAPB;
    unsigned cnt = overflow ? (unsigned)CAPB : cnt_raw;
    unsigned srcmask = (1u << SRC_BITS) - 1;
    const unsigned* bb = buf + (size_t)b * CAPB;

    for (unsigned i = tid; i < cnt; i += 512) {
        unsigned rec = bb[i];
        unsigned s  = rec & srcmask;
        unsigned tl = rec >> SRC_BITS;
        uint4 tv = t_pk4[s];
        unsigned* mp = mt + tl * MTS;
        atomicMax(mp + 0, fmap(bf_lo(tv.x)));
        atomicMax(mp + 1, fmap(bf_hi(tv.x)));
        atomicMax(mp + 2, fmap(bf_lo(tv.y)));
        atomicMax(mp + 3, fmap(bf_hi(tv.y)));
        atomicMax(mp + 4, fmap(bf_lo(tv.z)));
        atomicMax(mp + 5, fmap(bf_hi(tv.z)));
        atomicMax(mp + 6, fmap(bf_lo(tv.w)));
        atomicMax(mp + 7, fmap(bf_hi(tv.w)));
    }
    __syncthreads();

    int n0 = b << BSHIFT;
    for (int tl = tid; tl < BRANGE; tl += 512) {
        int n = n0 + tl;
        if (n < N) {
            const unsigned* ms = mt + tl * MTS;
            float v0 = funmap(ms[0]), v1 = funmap(ms[1]);
            float v2 = funmap(ms[2]), v3 = funmap(ms[3]);
            float v4 = funmap(ms[4]), v5 = funmap(ms[5]);
            float v6 = funmap(ms[6]), v7 = funmap(ms[7]);
            if (overflow) {                // rare exact path
                const unsigned* mu = m_u + (size_t)n * HD;
                v0 = fmaxf(v0, funmap(mu[0]));
                v1 = fmaxf(v1, funmap(mu[1]));
                v2 = fmaxf(v2, funmap(mu[2]));
                v3 = fmaxf(v3, funmap(mu[3]));
                v4 = fmaxf(v4, funmap(mu[4]));
                v5 = fmaxf(v5, funmap(mu[5]));
                v6 = fmaxf(v6, funmap(mu[6]));
                v7 = fmaxf(v7, funmap(mu[7]));
            }
            uint4 o;                       // lossless: maxes of bf16 values
            o.x = pack_bf16_rne(v0, v1);
            o.y = pack_bf16_rne(v2, v3);
            o.z = pack_bf16_rne(v4, v5);
            o.w = pack_bf16_rne(v6, v7);
            m_pk[n] = o;
        }
    }
}

// ---- Fallback path (old, proven) kernels: used only if packing/workspace fails ----

__global__ __launch_bounds__(256) void seg_max_kernel(
    const int* __restrict__ sources, const int* __restrict__ targets,
    const uint4* __restrict__ t_pk4, unsigned* __restrict__ m_u, int E)
{
    int e = blockIdx.x * 256 + threadIdx.x;
    if (e >= E) return;
    int s  = __builtin_nontemporal_load(sources + e);
    int tg = __builtin_nontemporal_load(targets + e);
    uint4 tv = t_pk4[s];
    unsigned* mp = m_u + (size_t)tg * HD;
    const uint4* m4 = (const uint4*)mp;
    uint4 c0 = m4[0];
    uint4 c1 = m4[1];
    unsigned f;
    f = fmap(bf_lo(tv.x)); if (f > c0.x) atomicMax(mp + 0, f);
    f = fmap(bf_hi(tv.x)); if (f > c0.y) atomicMax(mp + 1, f);
    f = fmap(bf_lo(tv.y)); if (f > c0.z) atomicMax(mp + 2, f);
    f = fmap(bf_hi(tv.y)); if (f > c0.w) atomicMax(mp + 3, f);
    f = fmap(bf_lo(tv.z)); if (f > c1.x) atomicMax(mp + 4, f);
    f = fmap(bf_hi(tv.z)); if (f > c1.y) atomicMax(mp + 5, f);
    f = fmap(bf_lo(tv.w)); if (f > c1.z) atomicMax(mp + 6, f);
    f = fmap(bf_hi(tv.w)); if (f > c1.w) atomicMax(mp + 7, f);
}

__global__ __launch_bounds__(256) void pack_m_kernel(
    const unsigned* __restrict__ m_u, uint4* __restrict__ m_pk, int N)
{
    int n = blockIdx.x * 256 + threadIdx.x;
    if (n >= N) return;
    const uint4* mu4 = (const uint4*)m_u + (size_t)n * 2;
    uint4 c0 = mu4[0];
    uint4 c1 = mu4[1];
    uint4 o;
    o.x = (__float_as_uint(funmap(c0.x)) >> 16) | (__float_as_uint(funmap(c0.y)) & 0xFFFF0000u);
    o.y = (__float_as_uint(funmap(c0.z)) >> 16) | (__float_as_uint(funmap(c0.w)) & 0xFFFF0000u);
    o.z = (__float_as_uint(funmap(c1.x)) >> 16) | (__float_as_uint(funmap(c1.y)) & 0xFFFF0000u);
    o.w = (__float_as_uint(funmap(c1.z)) >> 16) | (__float_as_uint(funmap(c1.w)) & 0xFFFF0000u);
    m_pk[n] = o;
}

// Phase C: out[e,h] = exp(t[src,h] - m[tgt,h]) * drop_mask[e,h].
// REVERTED to 1 edge/thread (r4-vs-r6 ledger: 2-edge costs ~+19 us — the strided
// 16B/lane-at-64B pattern quadruples touched lines per instruction). Cacheable
// stores; __expf (arg in [-2,0], error << bf16 tolerance).
__global__ __launch_bounds__(256) void finalize_kernel(
    const int* __restrict__ sources, const int* __restrict__ targets,
    const uint4* __restrict__ t_pk4, const uint4* __restrict__ m_pk,
    const float* __restrict__ dm, float* __restrict__ out, int E)
{
    int e = blockIdx.x * 256 + threadIdx.x;
    if (e >= E) return;
    int s  = __builtin_nontemporal_load(sources + e);
    int tg = __builtin_nontemporal_load(targets + e);
    uint4 tv = t_pk4[s];
    uint4 mv = m_pk[tg];
    const vf4* dm4 = (const vf4*)dm;
    vf4 d0 = dm4[(size_t)e * 2];      // heads 0..3
    vf4 d1 = dm4[(size_t)e * 2 + 1];  // heads 4..7
    vf4 o0, o1;
    o0.x = __expf(bf_lo(tv.x) - bf_lo(mv.x)) * d0.x;  // h0
    o0.y = __expf(bf_lo(tv.y) - bf_lo(mv.y)) * d0.y;  // h1
    o0.z = __expf(bf_lo(tv.z) - bf_lo(mv.z)) * d0.z;  // h2
    o0.w = __expf(bf_lo(tv.w) - bf_lo(mv.w)) * d0.w;  // h3
    o1.x = __expf(bf_hi(tv.x) - bf_hi(mv.x)) * d1.x;  // h4
    o1.y = __expf(bf_hi(tv.y) - bf_hi(mv.y)) * d1.y;  // h5
    o1.z = __expf(bf_hi(tv.z) - bf_hi(mv.z)) * d1.z;  // h6
    o1.w = __expf(bf_hi(tv.w) - bf_hi(mv.w)) * d1.w;  // h7
    vf4* out4 = (vf4*)out;
    out4[(size_t)e * 2]     = o0;
    out4[(size_t)e * 2 + 1] = o1;
}

extern "C" void kernel_launch(void* const* d_in, const int* in_sizes, int n_in,
                              void* d_out, int out_size, void* d_ws, size_t ws_size,
                              hipStream_t stream)
{
    const float* X       = (const float*)d_in[0];   // (B,N,H,D) fp32
    const float* Wk      = (const float*)d_in[1];   // (D,H,1)   fp32
    const int*   targets = (const int*)d_in[2];     // (B,E)
    const int*   sources = (const int*)d_in[3];     // (B,E)
    const float* dm      = (const float*)d_in[5];   // (B,E,H)

    int E = in_sizes[2];          // B=1
    int N = in_sizes[4];          // degree is (B,N)

    float* out = (float*)d_out;
    int blocksA = (N + 7) / 8;           // 4 waves/block, 2 nodes/wave
    int blocksE = (E + 255) / 256;       // finalize: 1 edge/thread

    // Binned-path parameters.
    int NB = (N + BRANGE - 1) >> BSHIFT;              // buckets of 256 nodes
    int SRC_BITS = 1;
    while ((1 << SRC_BITS) < N && SRC_BITS < 31) ++SRC_BITS;
    bool packable = (NB <= NBMAX) && (SRC_BITS + BSHIFT <= 32);
    long long capll = ((long long)(E + NB - 1) / (NB > 0 ? NB : 1));
    capll = (capll * 3) / 2;                          // mean * 1.5
    capll = (capll + 255) & ~255LL;
    int CAPB = (int)capll;

    // Per-set workspace layout (bytes): t_pk 16N | m_u 32N | m_pk 16N | gcnt 4N | buf NB*CAPB*4
    // TWO sets: set 0 = real pipeline, set 1 = timing-probe replicas (A2/B2/R2 launched
    // after finalize; outputs unused; they make the invisible kernels' cost measurable:
    // dur_r7 - dur_r6 ~= A+B+R, and any kernel >=125 us surfaces in top-5 with counters).
    size_t set_sz = (size_t)N * 68 + (size_t)NB * (size_t)CAPB * 4;
    set_sz = (set_sz + 255) & ~(size_t)255;

    char* w = (char*)d_ws;

    if (packable && ws_size >= 2 * set_sz) {
        unsigned* t_pk = (unsigned*)w;
        unsigned* m_u  = (unsigned*)(w + (size_t)N * 16);
        uint4*    m_pk = (uint4*)  (w + (size_t)N * 48);
        unsigned* gcnt = (unsigned*)(w + (size_t)N * 64);
        unsigned* buf  = (unsigned*)(w + (size_t)N * 68);

        char* w2 = w + set_sz;
        unsigned* t_pk2 = (unsigned*)w2;
        unsigned* m_u2  = (unsigned*)(w2 + (size_t)N * 16);
        uint4*    m_pk2 = (uint4*)  (w2 + (size_t)N * 48);
        unsigned* gcnt2 = (unsigned*)(w2 + (size_t)N * 64);
        unsigned* buf2  = (unsigned*)(w2 + (size_t)N * 68);

        int blocksB = (E + 4095) / 4096;

        // Real pipeline.
        attn_tanh_kernel<<<blocksA, 256, 0, stream>>>(X, Wk, t_pk, (uint2*)m_u, gcnt, NB, N);
        bin_kernel<<<blocksB, 256, 0, stream>>>(sources, targets, gcnt, buf,
                                                (const uint4*)t_pk, m_u, NB, CAPB, SRC_BITS, E);
        reduce_kernel<<<NB, 512, 0, stream>>>(gcnt, buf, (const uint4*)t_pk, m_u,
                                              m_pk, CAPB, SRC_BITS, N);
        finalize_kernel<<<blocksE, 256, 0, stream>>>(sources, targets, (const uint4*)t_pk,
                                                     m_pk, dm, out, E);

        // Timing probes (identical kernels, disjoint buffers, outputs unused).
        attn_tanh_kernel<<<blocksA, 256, 0, stream>>>(X, Wk, t_pk2, (uint2*)m_u2, gcnt2, NB, N);
        bin_kernel<<<blocksB, 256, 0, stream>>>(sources, targets, gcnt2, buf2,
                                                (const uint4*)t_pk2, m_u2, NB, CAPB, SRC_BITS, E);
        reduce_kernel<<<NB, 512, 0, stream>>>(gcnt2, buf2, (const uint4*)t_pk2, m_u2,
                                              m_pk2, CAPB, SRC_BITS, N);
    } else if (packable && ws_size >= set_sz) {
        // No probe space: plain binned pipeline.
        unsigned* t_pk = (unsigned*)w;
        unsigned* m_u  = (unsigned*)(w + (size_t)N * 16);
        uint4*    m_pk = (uint4*)  (w + (size_t)N * 48);
        unsigned* gcnt = (unsigned*)(w + (size_t)N * 64);
        unsigned* buf  = (unsigned*)(w + (size_t)N * 68);

        int blocksB = (E + 4095) / 4096;
        attn_tanh_kernel<<<blocksA, 256, 0, stream>>>(X, Wk, t_pk, (uint2*)m_u, gcnt, NB, N);
        bin_kernel<<<blocksB, 256, 0, stream>>>(sources, targets, gcnt, buf,
                                                (const uint4*)t_pk, m_u, NB, CAPB, SRC_BITS, E);
        reduce_kernel<<<NB, 512, 0, stream>>>(gcnt, buf, (const uint4*)t_pk, m_u,
                                              m_pk, CAPB, SRC_BITS, N);
        finalize_kernel<<<blocksE, 256, 0, stream>>>(sources, targets, (const uint4*)t_pk,
                                                     m_pk, dm, out, E);
    } else {
        // Fallback: proven atomicMax path (identical numerics).
        unsigned* t_pk = (unsigned*)w;
        unsigned* m_u  = (unsigned*)(w + (size_t)N * 16);
        uint4*    m_pk = (uint4*)  (w + (size_t)N * 48);

        attn_tanh_kernel<<<blocksA, 256, 0, stream>>>(X, Wk, t_pk, (uint2*)m_u, nullptr, 0, N);
        seg_max_kernel<<<blocksE, 256, 0, stream>>>(sources, targets, (const uint4*)t_pk, m_u, E);
        int blocksN = (N + 255) / 256;
        pack_m_kernel<<<blocksN, 256, 0, stream>>>(m_u, m_pk, N);
        finalize_kernel<<<blocksE, 256, 0, stream>>>(sources, targets, (const uint4*)t_pk,
                                                     m_pk, dm, out, E);
    }
}